// Round 2
// baseline (25580.061 us; speedup 1.0000x reference)
//
#include <hip/hip_runtime.h>

// ============================================================================
// Bidirectional 2-layer LSTM, T=1024 B=64 I=H=512, fp32 in/out.
// Round 2: kernel-per-timestep, hazard-safe MFMA via data-dependent nop asm.
// Gate-packed bf16 MFMA:
//   D[16 gate rows x 16 batch] = Wpack[16 x K] * X^T[K x 16],  K = Kx + 512
// Packed row r = q*4+gate within each 16-row group -> each lane's 4 acc regs
// are (i,f,g,o) for one (batch, h-col) pair (C/D: col=lane&15, row=lq*4+reg).
// All MFMA inputs are VMEM loads (layer-1 h_prev comes from a bf16 parity
// ring written at the previous step) -> no VALU-write->MFMA-read hazards.
// ============================================================================

using bfrag = __attribute__((ext_vector_type(8))) short;   // 8 x bf16 bits
using facc  = __attribute__((ext_vector_type(4))) float;   // 4 x f32 acc

#define TT 1024
#define NB 64

// Data-dependent hazard fences: ordering enforced via SSA dep on the value.
#define FENCE_PRE(v)  asm volatile("s_nop 3" : "+v"(v))            // VALU->MFMA srcC
#define FENCE_POST(v) asm volatile("s_nop 7\n\ts_nop 7" : "+v"(v)) // MFMA D->VALU

__device__ __forceinline__ unsigned short f2bf(float f) {
  union { float f; unsigned u; } v; v.f = f;
  unsigned r = v.u + 0x7fffu + ((v.u >> 16) & 1u);   // RNE
  return (unsigned short)(r >> 16);
}
__device__ __forceinline__ float sigm(float x)  { return 1.f / (1.f + __expf(-x)); }
__device__ __forceinline__ float tanhf_(float x){ return 1.f - 2.f / (__expf(2.f * x) + 1.f); }

__device__ __forceinline__ facc mfma_bf16(bfrag a, bfrag b, facc c) {
  asm("v_mfma_f32_16x16x32_bf16 %0, %1, %2, %0" : "+v"(c) : "v"(a), "v"(b));
  return c;
}

// ---------------------------------------------------------------- prep ----
__global__ __launch_bounds__(256) void k_cvt_x(const float* __restrict__ x,
                                               unsigned short* __restrict__ xb) {
  int i = blockIdx.x * 256 + threadIdx.x;          // 8,388,608 threads x 4 elems
  float4 v = reinterpret_cast<const float4*>(x)[i];
  ushort4 o;
  o.x = f2bf(v.x); o.y = f2bf(v.y); o.z = f2bf(v.z); o.w = f2bf(v.w);
  reinterpret_cast<ushort4*>(xb)[i] = o;
}

__global__ __launch_bounds__(256) void k_init(const float* __restrict__ h0,
                                              const float* __restrict__ c0,
                                              unsigned short* __restrict__ h0b,
                                              float* __restrict__ C4) {
  int i = blockIdx.x * 256 + threadIdx.x;          // 32768 = 64*512
  h0b[i] = f2bf(h0[i]);
  float c = c0[i];
  C4[i] = c; C4[32768 + i] = c; C4[65536 + i] = c; C4[98304 + i] = c;
}

// Pack W rows: R = g*16 + (q*4 + gate), row = [W_ih[srow] | W_hh[srow]] bf16.
template <int KX>
__global__ __launch_bounds__(256) void k_pack(const float* __restrict__ Wih,
                                              const float* __restrict__ Whh,
                                              const float* __restrict__ bias,
                                              unsigned short* __restrict__ PW,
                                              float* __restrict__ PB) {
  constexpr int K = KX + 512;
  int tid = blockIdx.x * 256 + threadIdx.x;        // exact grid: 2048*K threads
  int R = tid / K;
  int k = tid - R * K;
  int g = R >> 4, r = R & 15;
  int q = r >> 2, gate = r & 3;
  int srow = gate * 512 + (g * 4 + q);             // PyTorch gate order i,f,g,o
  float v = (k < KX) ? Wih[srow * KX + k] : Whh[srow * 512 + (k - KX)];
  PW[tid] = f2bf(v);
  if (k == 0) PB[R] = bias[srow];
}

// ---------------------------------------------------------------- step ----
// grid = 256 blocks x 256 thr: bid>>7 = dir (0 fwd / 1 bwd), bid&127 = h-col
// group (4 h-cols). 4 waves = 4 batch tiles of 16.
template <int LAYER>
__global__ __launch_bounds__(256) void k_step(
    int s,
    const unsigned short* __restrict__ xin,  // layer0: x_bf [T][64][512]; layer1: y0 [T][64][1024]
    unsigned short* __restrict__ y0,         // [T][64][1024] bf16 (layer0 out)
    float* __restrict__ dout,                // d_out: y1 | hn | cn
    const unsigned short* __restrict__ h0b,  // [64][512] bf16
    float* __restrict__ C4,                  // [4][64][512] f32 c-state
    unsigned short* __restrict__ hb,         // [2 parity][2 dir][64][512] bf16 (layer1 ring)
    const unsigned short* __restrict__ PWf, const unsigned short* __restrict__ PWb,
    const float* __restrict__ PBf, const float* __restrict__ PBb) {
  constexpr int KX = (LAYER == 0) ? 512 : 1024;
  constexpr int K  = KX + 512;

  const int bid  = blockIdx.x;
  const int dir  = bid >> 7;
  const int hg   = bid & 127;
  const int t    = dir ? (TT - 1 - s) : s;
  const int wave = threadIdx.x >> 6;
  const int lane = threadIdx.x & 63;
  const int lr   = lane & 15;     // A gate-row in tile / B batch col / C col
  const int lq   = lane >> 4;     // k-subgroup; C rows lq*4..lq*4+3
  const int b    = wave * 16 + lr;
  const bool first = (s == 0);
  const int tprev  = dir ? (t + 1) : (t - 1);

  const unsigned short* pw = dir ? PWb : PWf;
  const float* pb          = dir ? PBb : PBf;
  const unsigned short* Abase = pw + (size_t)(hg * 16 + lr) * K + lq * 8;

  const unsigned short* xrow = xin + ((size_t)t * NB + b) * (size_t)KX + lq * 8;

  const unsigned short* hrow;
  if (first)            hrow = h0b + (size_t)b * 512 + lq * 8;
  else if (LAYER == 0)  hrow = y0 + ((size_t)tprev * NB + b) * 1024 + dir * 512 + lq * 8;
  else                  hrow = hb + (size_t)((((s & 1) ^ 1) * 2 + dir)) * 32768 + (size_t)b * 512 + lq * 8;

  facc acc = {0.f, 0.f, 0.f, 0.f};
  FENCE_PRE(acc);                // VALU zero-init -> MFMA srcC wait states

#pragma unroll 8
  for (int kk = 0; kk < KX / 32; ++kk) {
    bfrag a = *reinterpret_cast<const bfrag*>(Abase + kk * 32);
    bfrag x = *reinterpret_cast<const bfrag*>(xrow + kk * 32);
    acc = mfma_bf16(a, x, acc);
  }
#pragma unroll 8
  for (int kk = 0; kk < 16; ++kk) {
    bfrag a = *reinterpret_cast<const bfrag*>(Abase + KX + kk * 32);
    bfrag h = *reinterpret_cast<const bfrag*>(hrow + kk * 32);
    acc = mfma_bf16(a, h, acc);
  }
  FENCE_POST(acc);               // MFMA D -> VALU read wait states

  // lane-local gates: acc[v] = gate v (i,f,g,o) for (b, hcol)
  const int hcol = hg * 4 + lq;
  const int scan = LAYER * 2 + dir;
  float4 bias = *reinterpret_cast<const float4*>(pb + hg * 16 + lq * 4);
  float ig = sigm(acc[0] + bias.x);
  float fg = sigm(acc[1] + bias.y);
  float gv = tanhf_(acc[2] + bias.z);
  float og = sigm(acc[3] + bias.w);
  const int cidx = scan * 32768 + b * 512 + hcol;
  float c2 = fg * C4[cidx] + ig * gv;
  float h2 = og * tanhf_(c2);
  C4[cidx] = c2;

  const size_t orow = ((size_t)t * NB + b) * 1024 + dir * 512 + hcol;
  if (LAYER == 0) {
    y0[orow] = f2bf(h2);
  } else {
    dout[orow] = h2;
    hb[(size_t)((s & 1) * 2 + dir) * 32768 + (size_t)b * 512 + hcol] = f2bf(h2);
  }

  if (s == TT - 1) {  // final carry -> hn / cn
    const size_t oh = ((size_t)LAYER * NB + b) * 1024 + dir * 512 + hcol;
    dout[67108864 + oh] = h2;
    dout[67239936 + oh] = c2;
  }
}

// -------------------------------------------------------------- launch ----
extern "C" void kernel_launch(void* const* d_in, const int* in_sizes, int n_in,
                              void* d_out, int out_size, void* d_ws, size_t ws_size,
                              hipStream_t stream) {
  (void)in_sizes; (void)n_in; (void)out_size; (void)ws_size;
  const float* x  = (const float*)d_in[0];
  const float* h0 = (const float*)d_in[1];
  const float* c0 = (const float*)d_in[2];
  const float* W[12];
  for (int i = 0; i < 12; ++i) W[i] = (const float*)d_in[3 + i];
  // W: Wih0f,Whh0f,b0f, Wih0b,Whh0b,b0b, Wih1f,Whh1f,b1f, Wih1b,Whh1b,b1b

  // ws layout (bytes), total ~213 MB
  char* ws = (char*)d_ws;
  unsigned short* xb   = (unsigned short*)(ws + 0ull);           //  64 MB x bf16
  unsigned short* y0   = (unsigned short*)(ws + 67108864ull);    // 128 MB layer0 out bf16
  unsigned short* h0b  = (unsigned short*)(ws + 201326592ull);   //  64 KB
  unsigned short* PW0F = (unsigned short*)(ws + 201392128ull);   //   4 MB
  unsigned short* PW0B = (unsigned short*)(ws + 205586432ull);   //   4 MB
  unsigned short* PW1F = (unsigned short*)(ws + 209780736ull);   //   6 MB
  unsigned short* PW1B = (unsigned short*)(ws + 216072192ull);   //   6 MB
  float*          PB   = (float*)(ws + 222363648ull);            //  32 KB (4 x 2048)
  float*          C4   = (float*)(ws + 222396416ull);            // 512 KB c-state
  unsigned short* hb   = (unsigned short*)(ws + 222920704ull);   // 256 KB layer1 h ring
  float* dout = (float*)d_out;

  k_cvt_x<<<32768, 256, 0, stream>>>(x, xb);
  k_init<<<128, 256, 0, stream>>>(h0, c0, h0b, C4);
  k_pack<512> <<<8192, 256, 0, stream>>>(W[0], W[1],  W[2],  PW0F, PB + 0);
  k_pack<512> <<<8192, 256, 0, stream>>>(W[3], W[4],  W[5],  PW0B, PB + 2048);
  k_pack<1024><<<12288, 256, 0, stream>>>(W[6], W[7],  W[8],  PW1F, PB + 4096);
  k_pack<1024><<<12288, 256, 0, stream>>>(W[9], W[10], W[11], PW1B, PB + 6144);

  for (int s = 0; s < TT; ++s)
    k_step<0><<<256, 256, 0, stream>>>(s, xb, y0, dout, h0b, C4, hb, PW0F, PW0B, PB + 0,    PB + 2048);
  for (int s = 0; s < TT; ++s)
    k_step<1><<<256, 256, 0, stream>>>(s, y0, y0, dout, h0b, C4, hb, PW1F, PW1B, PB + 4096, PB + 6144);
}

// Round 4
// 23472.058 us; speedup vs baseline: 1.0898x; 1.0898x over previous
//
#include <hip/hip_runtime.h>

// ============================================================================
// Bidirectional 2-layer LSTM, T=1024 B=64 I=H=512, fp32 in/out.
// Round 4: persistent cooperative scan (2 launches), LDS-resident weights,
// device-scope atomic barrier per (dir, step), x-part MFMAs hide barrier wait.
// (Round 3 + fence spelling fix: __builtin_amdgcn_fence.)
// Gate-packed bf16 MFMA: D[16 gate rows x 16 batch] = Wpack[16xK] * X^T[Kx16];
// packed row r = q*4+gate -> lane's 4 acc regs = (i,f,g,o) for one (b, hcol).
// Block = 32 gate-rows x 64 batches = 8 waves; weights [32 x K] in LDS, tiled
// [chunk=8k x 32rows][pad 32B] -> 2-way-bank reads. c-state in registers.
// ============================================================================

using bfrag = __attribute__((ext_vector_type(8))) short;   // 8 x bf16 bits
using facc  = __attribute__((ext_vector_type(4))) float;   // 4 x f32 acc

#define TT 1024
#define NB 64

__device__ __forceinline__ unsigned short f2bf(float f) {
  union { float f; unsigned u; } v; v.f = f;
  unsigned r = v.u + 0x7fffu + ((v.u >> 16) & 1u);   // RNE
  return (unsigned short)(r >> 16);
}
__device__ __forceinline__ float sigm(float x)  { return 1.f / (1.f + __expf(-x)); }
__device__ __forceinline__ float tanhf_(float x){ return 1.f - 2.f / (__expf(2.f * x) + 1.f); }

__device__ __forceinline__ facc mfma_bf16(bfrag a, bfrag b, facc c) {
  asm("v_mfma_f32_16x16x32_bf16 %0, %1, %2, %0" : "+v"(c) : "v"(a), "v"(b));
  return c;
}

// ---------------------------------------------------------------- prep ----
__global__ __launch_bounds__(256) void k_cvt_x(const float* __restrict__ x,
                                               unsigned short* __restrict__ xb) {
  int i = blockIdx.x * 256 + threadIdx.x;          // 8,388,608 threads x 4 elems
  float4 v = reinterpret_cast<const float4*>(x)[i];
  ushort4 o;
  o.x = f2bf(v.x); o.y = f2bf(v.y); o.z = f2bf(v.z); o.w = f2bf(v.w);
  reinterpret_cast<ushort4*>(xb)[i] = o;
}

__global__ __launch_bounds__(256) void k_init(const float* __restrict__ h0,
                                              unsigned short* __restrict__ h0b,
                                              unsigned* __restrict__ cnts) {
  int i = blockIdx.x * 256 + threadIdx.x;          // 32768 = 64*512
  h0b[i] = f2bf(h0[i]);
  if (i < 4) cnts[i * 1024] = 0;                   // 4 counters, 4KB apart
}

// Pack weights, gate-interleaved + chunk-tiled for LDS:
//   packed row R = g*16 + q*4 + gate  (g = hcol/4, q = hcol%4)
//   block gb owns rows [gb*32, gb*32+32); chunk cc = k/8 (8 k x 32 rows),
//   chunk stride 272 ushorts (256 data + 16 pad -> LDS bank spread).
template <int KX>
__global__ __launch_bounds__(256) void k_pack(const float* __restrict__ Wih,
                                              const float* __restrict__ Whh,
                                              const float* __restrict__ bias,
                                              unsigned short* __restrict__ PW,
                                              float* __restrict__ PB) {
  constexpr int K = KX + 512;
  int tid = blockIdx.x * 256 + threadIdx.x;        // exact grid: 2048*K threads
  int R = tid / K;
  int k = tid - R * K;
  int g = R >> 4, r = R & 15;
  int q = r >> 2, gate = r & 3;
  int srow = gate * 512 + (g * 4 + q);             // PyTorch gate order i,f,g,o
  float v = (k < KX) ? Wih[srow * KX + k] : Whh[srow * 512 + (k - KX)];
  int gb = R >> 5, rr = R & 31, cc = k >> 3;
  PW[(size_t)gb * (K / 8) * 272 + cc * 272 + rr * 8 + (k & 7)] = f2bf(v);
  if (k == 0) PB[R] = bias[srow];
}

// ---------------------------------------------------------------- scan ----
// grid = 128 blocks (dir = bid>>6, gb = bid&63) x 512 threads (8 waves).
// wave w: grT = w&1 (16-row half of the 32 gate-rows), bT = w>>1 (batch tile).
template <int LAYER>
__global__ __launch_bounds__(512, 2) void k_scan(
    const unsigned short* __restrict__ xin,  // L0: xb [T][64][512]; L1: y0 [T][64][1024]
    unsigned short* __restrict__ y0,         // L0 out [T][64][1024] bf16 (null for L1)
    float* __restrict__ dout,                // d_out: y1 | hn | cn
    const unsigned short* __restrict__ h0b,  // [64][512] bf16
    const float* __restrict__ c0,            // [64][512] f32
    unsigned short* __restrict__ hb,         // [2 parity][2 dir][64][512] bf16 (L1 ring)
    const unsigned short* __restrict__ PWf, const unsigned short* __restrict__ PWb,
    const float* __restrict__ PBf, const float* __restrict__ PBb,
    unsigned* __restrict__ cntF, unsigned* __restrict__ cntB) {
  constexpr int KX = (LAYER == 0) ? 512 : 1024;
  constexpr int K  = KX + 512;
  constexpr int CH = K / 8;                  // chunks
  extern __shared__ unsigned short Wlds[];   // CH*272 ushorts

  const int bid = blockIdx.x;
  const int dir = bid >> 6;
  const int gb  = bid & 63;
  const int tid = threadIdx.x;
  unsigned* cnt = dir ? cntB : cntF;
  const unsigned short* pw = (dir ? PWb : PWf) + (size_t)gb * CH * 272;
  const float* pb          = dir ? PBb : PBf;

  // stage this block's weight slice into LDS (once)
  for (int i = tid; i < CH * 34; i += 512)
    reinterpret_cast<bfrag*>(Wlds)[i] = reinterpret_cast<const bfrag*>(pw)[i];
  __syncthreads();

  const int w = tid >> 6, lane = tid & 63;
  const int lr = lane & 15, lq = lane >> 4;
  const int grT = w & 1, bT = w >> 1;
  const int b    = bT * 16 + lr;
  const int hcol = (gb * 2 + grT) * 4 + lq;
  const int ldsBase = grT * 128 + lr * 8;    // elem offset within chunk
  const float4 bias = *reinterpret_cast<const float4*>(pb + (gb * 2 + grT) * 16 + lq * 4);
  float c = c0[b * 512 + hcol];

  for (int s = 0; s < TT; ++s) {
    const int t = dir ? (TT - 1 - s) : s;

    // ---- x-part: independent of h(s-1), overlaps other blocks' arrival ----
    const unsigned short* xrow = xin + ((size_t)t * NB + b) * KX + lq * 8;
    facc a0 = {0.f, 0.f, 0.f, 0.f}, a1 = {0.f, 0.f, 0.f, 0.f};
    asm volatile("s_nop 3" : "+v"(a0), "+v"(a1));   // VALU init -> MFMA srcC
#pragma unroll 8
    for (int kk = 0; kk < KX / 32; ++kk) {
      bfrag a = *reinterpret_cast<const bfrag*>(Wlds + (size_t)(kk * 4 + lq) * 272 + ldsBase);
      bfrag x = *reinterpret_cast<const bfrag*>(xrow + kk * 32);
      if (kk & 1) a1 = mfma_bf16(a, x, a1); else a0 = mfma_bf16(a, x, a0);
    }

    // ---- wait for h(s-1) from all blocks of this dir ----
    if (s > 0) {
      if (tid == 0) {
        const unsigned tgt = 64u * (unsigned)s;
        while (__hip_atomic_load(cnt, __ATOMIC_RELAXED, __HIP_MEMORY_SCOPE_AGENT) < tgt)
          __builtin_amdgcn_s_sleep(2);
        __builtin_amdgcn_fence(__ATOMIC_ACQUIRE, "agent");  // vmcnt(0)+buffer_inv
      }
      __syncthreads();
    }

    // ---- h-part ----
    const int tp = dir ? (t + 1) : (t - 1);
    const unsigned short* hrow;
    if (s == 0)               hrow = h0b + (size_t)b * 512 + lq * 8;
    else if constexpr (LAYER == 0)
                              hrow = y0 + ((size_t)tp * NB + b) * 1024 + dir * 512 + lq * 8;
    else                      hrow = hb + (size_t)(((s & 1) ^ 1) * 2 + dir) * 32768 + (size_t)b * 512 + lq * 8;
#pragma unroll 8
    for (int kk = 0; kk < 16; ++kk) {
      bfrag a = *reinterpret_cast<const bfrag*>(Wlds + (size_t)(KX / 8 + kk * 4 + lq) * 272 + ldsBase);
      bfrag h = *reinterpret_cast<const bfrag*>(hrow + kk * 32);
      if (kk & 1) a1 = mfma_bf16(a, h, a1); else a0 = mfma_bf16(a, h, a0);
    }
    asm volatile("s_nop 7\n\ts_nop 7" : "+v"(a0), "+v"(a1));  // MFMA D -> VALU

    // ---- gates (lane-local i,f,g,o), state update, publish h ----
    float ig = sigm(a0[0] + a1[0] + bias.x);
    float fg = sigm(a0[1] + a1[1] + bias.y);
    float gv = tanhf_(a0[2] + a1[2] + bias.z);
    float og = sigm(a0[3] + a1[3] + bias.w);
    c = fg * c + ig * gv;
    const float h2 = og * tanhf_(c);

    const size_t orow = ((size_t)t * NB + b) * 1024 + dir * 512 + hcol;
    if constexpr (LAYER == 0) {
      __hip_atomic_store(&y0[orow], f2bf(h2), __ATOMIC_RELAXED, __HIP_MEMORY_SCOPE_AGENT);
    } else {
      dout[orow] = h2;
      __hip_atomic_store(&hb[(size_t)((s & 1) * 2 + dir) * 32768 + (size_t)b * 512 + hcol],
                         f2bf(h2), __ATOMIC_RELAXED, __HIP_MEMORY_SCOPE_AGENT);
    }
    if (s == TT - 1) {  // final carry -> hn / cn
      const size_t oh = ((size_t)LAYER * NB + b) * 1024 + dir * 512 + hcol;
      dout[67108864 + oh] = h2;
      dout[67239936 + oh] = c;
    }

    // ---- arrive ----
    __syncthreads();                         // all waves' work for step s done
    if (tid == 0)
      __hip_atomic_fetch_add(cnt, 1u, __ATOMIC_RELEASE, __HIP_MEMORY_SCOPE_AGENT);
  }
}

// -------------------------------------------------------------- launch ----
extern "C" void kernel_launch(void* const* d_in, const int* in_sizes, int n_in,
                              void* d_out, int out_size, void* d_ws, size_t ws_size,
                              hipStream_t stream) {
  (void)in_sizes; (void)n_in; (void)out_size; (void)ws_size;
  const float* x  = (const float*)d_in[0];
  const float* h0 = (const float*)d_in[1];
  const float* c0 = (const float*)d_in[2];
  const float* W[12];
  for (int i = 0; i < 12; ++i) W[i] = (const float*)d_in[3 + i];
  // W: Wih0f,Whh0f,b0f, Wih0b,Whh0b,b0b, Wih1f,Whh1f,b1f, Wih1b,Whh1b,b1b

  // ws layout (bytes), total ~214 MB
  char* ws = (char*)d_ws;
  unsigned short* xb   = (unsigned short*)(ws + 0ull);           //  64 MB x bf16
  unsigned short* y0   = (unsigned short*)(ws + 67108864ull);    // 128 MB layer0 out bf16
  unsigned short* h0b  = (unsigned short*)(ws + 201326592ull);   //  64 KB
  unsigned short* PW0F = (unsigned short*)(ws + 201392128ull);   // 4.25 MB (64*128*272*2)
  unsigned short* PW0B = (unsigned short*)(ws + 205848576ull);
  unsigned short* PW1F = (unsigned short*)(ws + 210305024ull);   // 6.38 MB (64*192*272*2)
  unsigned short* PW1B = (unsigned short*)(ws + 216989696ull);
  float*          PB   = (float*)(ws + 223674368ull);            //  32 KB (4 x 2048)
  unsigned short* hb   = (unsigned short*)(ws + 223707136ull);   // 256 KB layer1 h ring
  unsigned*       cnts = (unsigned*)(ws + 223969280ull);         //  16 KB (4 x 4KB apart)
  float* dout = (float*)d_out;

  k_cvt_x<<<32768, 256, 0, stream>>>(x, xb);
  k_init<<<128, 256, 0, stream>>>(h0, h0b, cnts);
  k_pack<512> <<<8192, 256, 0, stream>>>(W[0], W[1],  W[2],  PW0F, PB + 0);
  k_pack<512> <<<8192, 256, 0, stream>>>(W[3], W[4],  W[5],  PW0B, PB + 2048);
  k_pack<1024><<<12288, 256, 0, stream>>>(W[6], W[7],  W[8],  PW1F, PB + 4096);
  k_pack<1024><<<12288, 256, 0, stream>>>(W[9], W[10], W[11], PW1B, PB + 6144);

  // ---- persistent cooperative scans (one per layer) ----
  const unsigned short* xin0 = xb;
  const unsigned short* xin1 = y0;
  unsigned short* y0m = y0;
  unsigned short* y0n = nullptr;
  const unsigned short* h0bc = h0b;
  unsigned* c00 = cnts + 0;    unsigned* c01 = cnts + 1024;
  unsigned* c10 = cnts + 2048; unsigned* c11 = cnts + 3072;
  const unsigned short *pw0f = PW0F, *pw0b = PW0B, *pw1f = PW1F, *pw1b = PW1B;
  const float *pb0f = PB + 0, *pb0b = PB + 2048, *pb1f = PB + 4096, *pb1b = PB + 6144;

  void* args0[] = {(void*)&xin0, (void*)&y0m, (void*)&dout, (void*)&h0bc, (void*)&c0,
                   (void*)&hb, (void*)&pw0f, (void*)&pw0b, (void*)&pb0f, (void*)&pb0b,
                   (void*)&c00, (void*)&c01};
  void* args1[] = {(void*)&xin1, (void*)&y0n, (void*)&dout, (void*)&h0bc, (void*)&c0,
                   (void*)&hb, (void*)&pw1f, (void*)&pw1b, (void*)&pb1f, (void*)&pb1b,
                   (void*)&c10, (void*)&c11};

  (void)hipFuncSetAttribute((const void*)(&k_scan<0>),
                            hipFuncAttributeMaxDynamicSharedMemorySize, 69632);
  (void)hipFuncSetAttribute((const void*)(&k_scan<1>),
                            hipFuncAttributeMaxDynamicSharedMemorySize, 104448);
  (void)hipLaunchCooperativeKernel((const void*)(&k_scan<0>), dim3(128), dim3(512),
                                   args0, 69632, stream);
  (void)hipLaunchCooperativeKernel((const void*)(&k_scan<1>), dim3(128), dim3(512),
                                   args1, 104448, stream);
}